// Round 17
// baseline (2036.697 us; speedup 1.0000x reference)
//
#include <hip/hip_runtime.h>

#define NTH 512          // 8 waves -> 2 waves/SIMD resident (vs 1.25 at 320)
#define SPB 7            // samples per block; all unit maps <= 512, no stragglers
#define W66 66
#define PIX36 36
#define NPOS 18
#define FEAT 2376
#define TT 256
#define NSAMP 16384
#define CHU (SPB * W66)  // 462 channel units
#define SROW 2376        // floats per sample row; 2376%32=8
#define XPAD 8           // xft s-stride (pad 7 -> 8 for float4 access)

// ws float offsets
#define PACK_FLOATS (2 * NPOS * W66 * W66)    // 313632
#define C1P_OFF  PACK_FLOATS                  // 11616: c1p[L][i][cp][4]
#define C2P_OFF  (C1P_OFF + 11616)            // 23232: c2p[L][i][cp][8]
#define GI0_OFF  (C2P_OFF + 23232)            // 786432: gi0[16384][48]

static constexpr float KC[6] = {1.f, 0.5f, -0.5f, -1.f, -0.5f, 0.5f};
static constexpr float KS[6] = {0.f, 0.8660254037844386468f, 0.8660254037844386468f,
                                0.f, -0.8660254037844386468f, -0.8660254037844386468f};

__device__ __forceinline__ float gelu_f(float v) {
    return 0.5f * v * (1.f + erff(v * 0.70710678118654752440f));
}

__device__ __forceinline__ void load_row36(float* d, const float* p) {
    const float4* r = (const float4*)p;
    #pragma unroll
    for (int q = 0; q < 9; ++q) {
        float4 v = r[q];
        d[4*q] = v.x; d[4*q+1] = v.y; d[4*q+2] = v.z; d[4*q+3] = v.w;
    }
}

extern "C" __global__ void repack_kernel(
    const float* __restrict__ w1r0, const float* __restrict__ w1i0,
    const float* __restrict__ w2r0, const float* __restrict__ w2i0,
    const float* __restrict__ w1r1, const float* __restrict__ w1i1,
    const float* __restrict__ w2r1, const float* __restrict__ w2i1,
    const float* __restrict__ m0aw, const float* __restrict__ m1aw,
    const float* __restrict__ m0bw, const float* __restrict__ m1bw,
    const float* __restrict__ w0w,  const float* __restrict__ w1w,
    float* __restrict__ ws)
{
    int e = blockIdx.x * blockDim.x + threadIdx.x;
    const int TOT = 2 * NPOS * W66 * W66;
    if (e < TOT) {
        int L = e / (NPOS * W66 * W66);
        int r = e % (NPOS * W66 * W66);
        int p = r / (W66 * W66);
        int io = r % (W66 * W66);
        int i = io / W66, o = io % W66;
        int kx = p / 3, ky = p % 3;
        const float *wr, *wi;
        int kxw;
        if (L == 0) { if (kx < 3) { wr = w1r0; wi = w1i0; kxw = kx; } else { wr = w2r0; wi = w2i0; kxw = kx - 3; } }
        else        { if (kx < 3) { wr = w1r1; wi = w1i1; kxw = kx; } else { wr = w2r1; wi = w2i1; kxw = kx - 3; } }
        int src = ((i * W66 + o) * 3 + kxw) * 3 + ky;
        ws[(size_t)e * 2 + 0] = wr[src];
        ws[(size_t)e * 2 + 1] = wi[src];
    }
    if (e < 2 * 66 * 22) {        // c1p
        int L = e / (66 * 22); int r = e % (66 * 22);
        int i = r / 22, cp = r % 22;
        const float* mw = L ? m1aw : m0aw;
        float4 v;
        v.x = mw[(3*cp + 0) * 66 + i];
        v.y = mw[(3*cp + 1) * 66 + i];
        v.z = mw[(3*cp + 2) * 66 + i];
        v.w = 0.f;
        ((float4*)(ws + C1P_OFF))[e] = v;
    }
    if (e < 2 * 66 * 22) {        // c2p
        int L = e / (66 * 22); int r = e % (66 * 22);
        int i = r / 22, cp = r % 22;
        const float* mb = L ? m1bw : m0bw;
        const float* sk = L ? w1w : w0w;
        float4 a, b;
        a.x = mb[(3*cp + 0) * 66 + i]; a.y = mb[(3*cp + 1) * 66 + i];
        a.z = mb[(3*cp + 2) * 66 + i]; a.w = 0.f;
        b.x = sk[(3*cp + 0) * 66 + i]; b.y = sk[(3*cp + 1) * 66 + i];
        b.z = sk[(3*cp + 2) * 66 + i]; b.w = 0.f;
        ((float4*)(ws + C2P_OFF))[(size_t)e * 2 + 0] = a;
        ((float4*)(ws + C2P_OFF))[(size_t)e * 2 + 1] = b;
    }
}

extern "C" __global__ void __launch_bounds__(NTH, 1)
fno_kernel(const float* __restrict__ X, const float* __restrict__ p_w,
           const float* __restrict__ p_b, const float* __restrict__ ws,
           const float* __restrict__ m0ab, const float* __restrict__ m1ab,
           const float* __restrict__ m0bb, const float* __restrict__ m1bb,
           const float* __restrict__ w0b, const float* __restrict__ w1b,
           const float* __restrict__ gwi, const float* __restrict__ gbi,
           float* __restrict__ gi0out)
{
    extern __shared__ float sm[];
    float* A  = sm;                       // rows [s][ch][36], 7*2376 = 16632 floats
    float* Bb = sm + SPB * SROW;          // xft/oft float2 [p][ch][8] (19008 fl) OR rows
    // total 35640 floats = 142560 B (1 block/CU regardless)

    const int tid = threadIdx.x;
    const int n0 = blockIdx.x * SPB;
    const int s = tid % 7, ch = tid / 7;      // (s,ch) for embed/F/I
    const bool actC = tid < CHU;
    const bool vs = (n0 + s) < NSAMP;
    const int cs = tid % 7, ct = tid / 7;     // conv: (s, hp, cp)
    const int chp = ct % 3, ccp = ct / 3;

    // ---- embed -> A row ----
    if (actC) {
        float h[36];
        float pw0 = p_w[ch], pw1 = p_w[66 + ch], pw2 = p_w[132 + ch], pb = p_b[ch];
        if (vs) {
            const float4* xr = (const float4*)(X + (size_t)(n0 + s) * 36);
            #pragma unroll
            for (int q = 0; q < 9; ++q) {
                float4 v = xr[q];
                float vv[4] = {v.x, v.y, v.z, v.w};
                #pragma unroll
                for (int e = 0; e < 4; ++e) {
                    int pix = 4 * q + e;
                    int px = pix / 6, py = pix % 6;
                    h[pix] = fmaf(vv[e] + 0.01f, pw0,
                              fmaf(px * 0.2f, pw1, fmaf(py * 0.2f, pw2, pb)));
                }
            }
        } else {
            #pragma unroll
            for (int x = 0; x < 36; ++x) h[x] = 0.f;
        }
        float4* r = (float4*)(A + s * SROW + ch * 36);
        #pragma unroll
        for (int q = 0; q < 9; ++q)
            r[q] = make_float4(h[4*q], h[4*q+1], h[4*q+2], h[4*q+3]);
    }
    // no barrier: F reads only this thread's own A row.

    for (int L = 0; L < 2; ++L) {
        const float* mab = L ? m1ab : m0ab;
        const float* mbb = L ? m1bb : m0bb;
        const float* skb = L ? w1b : w0b;
        const float2* packL = ((const float2*)ws) + (size_t)L * NPOS * W66 * W66;
        const float4* c1p = (const float4*)(ws + C1P_OFF) + (size_t)L * 66 * 22;
        const float4* c2p = (const float4*)(ws + C2P_OFF) + (size_t)L * 66 * 22 * 2;

        // ---- F: separable forward DFT + in-reg stats -> xft [p][ch][8] ----
        if (actC) {
            float h[36];
            load_row36(h, A + s * SROW + ch * 36);
            float sum = 0.f, sq = 0.f;
            #pragma unroll
            for (int x = 0; x < 36; ++x) { sum += h[x]; sq = fmaf(h[x], h[x], sq); }
            float hm = sum * (1.f / 36.f);
            float hrs = rsqrtf(sq * (1.f / 36.f) - hm * hm + 1e-5f);
            float tr[6][3], ti[6][3];
            #pragma unroll
            for (int px = 0; px < 6; ++px) {
                float a0 = h[px*6+0], a1 = h[px*6+1], a2 = h[px*6+2];
                float a3 = h[px*6+3], a4 = h[px*6+4], a5 = h[px*6+5];
                float s14 = a1 + a4, d14 = a1 - a4, s25 = a2 + a5, d25 = a2 - a5;
                tr[px][0] = (a0 + a3) + s14 + s25;
                ti[px][0] = 0.f;
                tr[px][1] = (a0 - a3) + 0.5f * (d14 - d25);
                ti[px][1] = -0.8660254037844386468f * (d14 + d25);
                tr[px][2] = (a0 + a3) - 0.5f * (s14 + s25);
                ti[px][2] = -0.8660254037844386468f * (s14 - s25);
            }
            float2* xf = (float2*)Bb;
            #pragma unroll
            for (int kx = 0; kx < 6; ++kx) {
                #pragma unroll
                for (int ky = 0; ky < 3; ++ky) {
                    float xr = 0.f, xi = 0.f;
                    #pragma unroll
                    for (int px = 0; px < 6; ++px) {
                        const int m = (kx * px) % 6;
                        xr += tr[px][ky] * KC[m] + ti[px][ky] * KS[m];
                        xi += ti[px][ky] * KC[m] - tr[px][ky] * KS[m];
                    }
                    if (kx == 0 && ky == 0) xr -= 36.f * hm;
                    xf[((kx * 3 + ky) * 66 + ch) * XPAD + s] = make_float2(hrs * xr, hrs * xi);
                }
            }
        }
        __syncthreads();  // B1: xft ready

        // ---- M: channel mix, units (p, o-triple) = 396, single pass ----
        {
            const bool actM = tid < 396;
            float ar[3][7], ai[3][7];
            int p = 0, o0 = 0;
            if (actM) { p = tid / 22; o0 = (tid - p * 22) * 3; }
            if (actM) {
                #pragma unroll
                for (int j = 0; j < 3; ++j)
                    #pragma unroll
                    for (int q = 0; q < 7; ++q) { ar[j][q] = 0.f; ai[j][q] = 0.f; }
                const float2* xfp = (const float2*)Bb + (size_t)p * 66 * XPAD;
                const float2* wp = packL + (size_t)p * 66 * 66;
                #pragma unroll 3
                for (int i = 0; i < 66; ++i) {
                    const float4* xv = (const float4*)(xfp + i * XPAD);
                    float4 x0 = xv[0], x1 = xv[1], x2 = xv[2], x3 = xv[3];
                    float xr[7] = {x0.x, x0.z, x1.x, x1.z, x2.x, x2.z, x3.x};
                    float xi[7] = {x0.y, x0.w, x1.y, x1.w, x2.y, x2.w, x3.y};
                    float4 w01 = *(const float4*)(wp + i * 66 + o0);   // o0.re,o0.im,o1.re,o1.im
                    float2 w2  = wp[i * 66 + o0 + 2];
                    #pragma unroll
                    for (int q = 0; q < 7; ++q) {
                        ar[0][q] = fmaf(xr[q], w01.x, ar[0][q]); ar[0][q] = fmaf(xi[q], -w01.y, ar[0][q]);
                        ai[0][q] = fmaf(xr[q], w01.y, ai[0][q]); ai[0][q] = fmaf(xi[q],  w01.x, ai[0][q]);
                        ar[1][q] = fmaf(xr[q], w01.z, ar[1][q]); ar[1][q] = fmaf(xi[q], -w01.w, ar[1][q]);
                        ai[1][q] = fmaf(xr[q], w01.w, ai[1][q]); ai[1][q] = fmaf(xi[q],  w01.z, ai[1][q]);
                        ar[2][q] = fmaf(xr[q], w2.x, ar[2][q]);  ar[2][q] = fmaf(xi[q], -w2.y, ar[2][q]);
                        ai[2][q] = fmaf(xr[q], w2.y, ai[2][q]);  ai[2][q] = fmaf(xi[q],  w2.x, ai[2][q]);
                    }
                }
            }
            __syncthreads();  // B2: all xft reads done
            if (actM) {
                float2* xf = (float2*)Bb;
                #pragma unroll
                for (int j = 0; j < 3; ++j) {
                    float4* d = (float4*)(xf + ((size_t)p * 66 + o0 + j) * XPAD);
                    d[0] = make_float4(ar[j][0], ai[j][0], ar[j][1], ai[j][1]);
                    d[1] = make_float4(ar[j][2], ai[j][2], ar[j][3], ai[j][3]);
                    d[2] = make_float4(ar[j][4], ai[j][4], ar[j][5], ai[j][5]);
                    d[3] = make_float4(ar[j][6], ai[j][6], 0.f, 0.f);   // pad slot unread
                }
            }
        }
        __syncthreads();  // B3: oft ready

        // ---- I: kx-first inverse DFT + stats; writes NORMALIZED rows ----
        {
            float sp[36];
            if (actC) {
                const float2* xf = (const float2*)Bb;
                float ar0[6], ar1[6], ai1[6], ar2[6], ai2[6];
                #pragma unroll
                for (int px = 0; px < 6; ++px) {
                    ar0[px]=0.f; ar1[px]=0.f; ai1[px]=0.f; ar2[px]=0.f; ai2[px]=0.f;
                }
                #pragma unroll
                for (int kx = 0; kx < 6; ++kx) {
                    float2 o0 = xf[((kx * 3 + 0) * 66 + ch) * XPAD + s];
                    float2 o1 = xf[((kx * 3 + 1) * 66 + ch) * XPAD + s];
                    float2 o2 = xf[((kx * 3 + 2) * 66 + ch) * XPAD + s];
                    #pragma unroll
                    for (int px = 0; px < 6; ++px) {
                        const int m = (kx * px) % 6;
                        ar0[px] += o0.x * KC[m] - o0.y * KS[m];
                        ar1[px] += o1.x * KC[m] - o1.y * KS[m];
                        ai1[px] += o1.x * KS[m] + o1.y * KC[m];
                        ar2[px] += o2.x * KC[m] - o2.y * KS[m];
                        ai2[px] += o2.x * KS[m] + o2.y * KC[m];
                    }
                }
                float sum = 0.f, sq = 0.f;
                #pragma unroll
                for (int px = 0; px < 6; ++px) {
                    #pragma unroll
                    for (int py = 0; py < 6; ++py) {
                        const int m2 = (2 * py) % 6;
                        float sv = (1.f/36.f) * ar0[px]
                                 + (1.f/18.f) * (ar1[px] * KC[py] - ai1[px] * KS[py])
                                 + (1.f/18.f) * (ar2[px] * KC[m2] - ai2[px] * KS[m2]);
                        sp[px*6+py] = sv; sum += sv; sq = fmaf(sv, sv, sq);
                    }
                }
                float m = sum * (1.f / 36.f);
                float rs = rsqrtf(sq * (1.f / 36.f) - m * m + 1e-5f);
                #pragma unroll
                for (int x = 0; x < 36; ++x) sp[x] = (sp[x] - m) * rs;
            }
            __syncthreads();  // B4: all oft reads done
            if (actC) {
                float4* r = (float4*)(Bb + s * SROW + ch * 36);
                #pragma unroll
                for (int q = 0; q < 9; ++q)
                    r[q] = make_float4(sp[4*q], sp[4*q+1], sp[4*q+2], sp[4*q+3]);
            }
        }
        __syncthreads();  // B5: normalized rows ready

        // ---- C1: plain conv + gelu; units (s, cp, hp) = 462 ----
        {
            float acc[3][12];
            if (actC) {
                #pragma unroll
                for (int j = 0; j < 3; ++j)
                    #pragma unroll
                    for (int x = 0; x < 12; ++x) acc[j][x] = 0.f;
                #pragma unroll 4
                for (int i = 0; i < 66; ++i) {
                    float4 w = c1p[i * 22 + ccp];
                    const float4* xr = (const float4*)(Bb + cs * SROW + i * 36 + chp * 12);
                    #pragma unroll
                    for (int q = 0; q < 3; ++q) {
                        float4 v = xr[q];
                        float vv[4] = {v.x, v.y, v.z, v.w};
                        #pragma unroll
                        for (int e = 0; e < 4; ++e) {
                            acc[0][4*q+e] = fmaf(w.x, vv[e], acc[0][4*q+e]);
                            acc[1][4*q+e] = fmaf(w.y, vv[e], acc[1][4*q+e]);
                            acc[2][4*q+e] = fmaf(w.z, vv[e], acc[2][4*q+e]);
                        }
                    }
                }
                float b0 = mab[3*ccp], b1 = mab[3*ccp+1], b2 = mab[3*ccp+2];
                #pragma unroll
                for (int x = 0; x < 12; ++x) {
                    acc[0][x] = gelu_f(acc[0][x] + b0);
                    acc[1][x] = gelu_f(acc[1][x] + b1);
                    acc[2][x] = gelu_f(acc[2][x] + b2);
                }
            }
            __syncthreads();  // B6: all reads of normalized rows done
            if (actC) {
                #pragma unroll
                for (int j = 0; j < 3; ++j) {
                    float4* dst = (float4*)(Bb + cs * SROW + (3*ccp+j) * 36 + chp * 12);
                    dst[0] = make_float4(acc[j][0], acc[j][1], acc[j][2],  acc[j][3]);
                    dst[1] = make_float4(acc[j][4], acc[j][5], acc[j][6],  acc[j][7]);
                    dst[2] = make_float4(acc[j][8], acc[j][9], acc[j][10], acc[j][11]);
                }
            }
        }
        __syncthreads();  // B7: t ready

        // ---- C2: conv2 + skip + gelu ----
        {
            float acc[3][12];
            if (actC) {
                #pragma unroll
                for (int j = 0; j < 3; ++j)
                    #pragma unroll
                    for (int x = 0; x < 12; ++x) acc[j][x] = 0.f;
                #pragma unroll 3
                for (int i = 0; i < 66; ++i) {
                    float4 wy = c2p[(i * 22 + ccp) * 2 + 0];
                    float4 wk = c2p[(i * 22 + ccp) * 2 + 1];
                    const float4* tr4 = (const float4*)(Bb + cs * SROW + i * 36 + chp * 12);
                    const float4* ar4 = (const float4*)(A  + cs * SROW + i * 36 + chp * 12);
                    #pragma unroll
                    for (int q = 0; q < 3; ++q) {
                        float4 tv = tr4[q], av = ar4[q];
                        float tvv[4] = {tv.x, tv.y, tv.z, tv.w};
                        float avv[4] = {av.x, av.y, av.z, av.w};
                        #pragma unroll
                        for (int e = 0; e < 4; ++e) {
                            acc[0][4*q+e] = fmaf(wy.x, tvv[e], fmaf(wk.x, avv[e], acc[0][4*q+e]));
                            acc[1][4*q+e] = fmaf(wy.y, tvv[e], fmaf(wk.y, avv[e], acc[1][4*q+e]));
                            acc[2][4*q+e] = fmaf(wy.z, tvv[e], fmaf(wk.z, avv[e], acc[2][4*q+e]));
                        }
                    }
                }
                #pragma unroll
                for (int j = 0; j < 3; ++j) {
                    float bj = mbb[3*ccp+j] + skb[3*ccp+j];
                    #pragma unroll
                    for (int x = 0; x < 12; ++x) acc[j][x] = gelu_f(acc[j][x] + bj);
                }
            }
            __syncthreads();  // B8: all t/A reads done
            if (actC) {
                #pragma unroll
                for (int j = 0; j < 3; ++j) {
                    float4* dst = (float4*)(A + cs * SROW + (3*ccp+j) * 36 + chp * 12);
                    dst[0] = make_float4(acc[j][0], acc[j][1], acc[j][2],  acc[j][3]);
                    dst[1] = make_float4(acc[j][4], acc[j][5], acc[j][6],  acc[j][7]);
                    dst[2] = make_float4(acc[j][8], acc[j][9], acc[j][10], acc[j][11]);
                }
            }
        }
        __syncthreads();  // B9: A rows visible for next F
    }

    // ---- epilogue: gi0 = feats @ Wi0^T + bi0; units (third, es, g) = 1008, 2 passes ----
    #pragma unroll
    for (int rnd = 0; rnd < 2; ++rnd) {
        int u = tid + rnd * NTH;
        if (u < 1008) {
            int third = u / 336, r = u - third * 336;
            int es = r % 7, g = r / 7;
            const float* ab = A + es * SROW + third * 792;
            const float* wb = gwi + (size_t)g * FEAT + third * 792;
            float a0 = 0.f, a1 = 0.f, a2 = 0.f, a3 = 0.f;
            #pragma unroll 2
            for (int w = 0; w < 22; ++w) {
                const float4* ar4 = (const float4*)(ab + w * 36);
                const float4* wr4 = (const float4*)(wb + w * 36);
                #pragma unroll
                for (int q = 0; q < 9; ++q) {
                    float4 av = ar4[q], wv = wr4[q];
                    a0 = fmaf(av.x, wv.x, a0); a1 = fmaf(av.y, wv.y, a1);
                    a2 = fmaf(av.z, wv.z, a2); a3 = fmaf(av.w, wv.w, a3);
                }
            }
            Bb[u] = (a0 + a1) + (a2 + a3);
        }
    }
    __syncthreads();
    if (tid < 336) {
        int es = tid % 7, g = tid / 7;
        if (n0 + es < NSAMP)
            gi0out[(size_t)(n0 + es) * 48 + g] = Bb[tid] + Bb[tid + 336] + Bb[tid + 672] + gbi[g];
    }
}

// fused GRU0 + GRU1 + output linear; one block per batch element, one wave.
extern "C" __global__ void __launch_bounds__(64, 1)
gru_kernel(const float* __restrict__ gi0, const float* __restrict__ wh0,
           const float* __restrict__ bh0, const float* __restrict__ wi1,
           const float* __restrict__ wh1, const float* __restrict__ bi1,
           const float* __restrict__ bh1, const float* __restrict__ outw,
           const float* __restrict__ outb, float* __restrict__ y)
{
    int b = blockIdx.x;
    int g = threadIdx.x;
    int gw = (g < 48) ? g : 0;
    float rwh0[16], rwi1[16], rwh1[16];
    #pragma unroll
    for (int j = 0; j < 16; ++j) {
        rwh0[j] = wh0[gw * 16 + j];
        rwi1[j] = wi1[gw * 16 + j];
        rwh1[j] = wh1[gw * 16 + j];
    }
    float vbh0 = bh0[gw], vbi1 = bi1[gw], vbh1 = bh1[gw];
    float vow = (g < 16) ? outw[g] : 0.f;
    float ob = outb[0];
    float h0 = 0.f, h1 = 0.f;
    int base = b * TT;
    int j = g & 15;
    float cur = (g < 48) ? gi0[(size_t)base * 48 + g] : 0.f;
    for (int t = 0; t < TT; ++t) {
        int tn = (t + 1 < TT) ? t + 1 : t;
        float nxt = (g < 48) ? gi0[((size_t)base + tn) * 48 + g] : 0.f;
        float gh0 = vbh0;
        #pragma unroll
        for (int k = 0; k < 16; ++k) gh0 = fmaf(rwh0[k], __shfl(h0, k), gh0);
        float gir = __shfl(cur, j), giz = __shfl(cur, 16 + j), gin = __shfl(cur, 32 + j);
        float ghr = __shfl(gh0, j), ghz = __shfl(gh0, 16 + j), ghn = __shfl(gh0, 32 + j);
        float r = 1.f / (1.f + expf(-(gir + ghr)));
        float z = 1.f / (1.f + expf(-(giz + ghz)));
        float n = tanhf(gin + r * ghn);
        h0 = (1.f - z) * n + z * h0;
        float gi1 = vbi1, gh1 = vbh1;
        #pragma unroll
        for (int k = 0; k < 16; ++k) {
            gi1 = fmaf(rwi1[k], __shfl(h0, k), gi1);
            gh1 = fmaf(rwh1[k], __shfl(h1, k), gh1);
        }
        float air = __shfl(gi1, j) + __shfl(gh1, j);
        float aiz = __shfl(gi1, 16 + j) + __shfl(gh1, 16 + j);
        float r1 = 1.f / (1.f + expf(-air));
        float z1 = 1.f / (1.f + expf(-aiz));
        float n1 = tanhf(__shfl(gi1, 32 + j) + r1 * __shfl(gh1, 32 + j));
        h1 = (1.f - z1) * n1 + z1 * h1;
        float v = h1 * vow;
        #pragma unroll
        for (int off = 32; off; off >>= 1) v += __shfl_xor(v, off);
        if (g == 0) y[base + t] = v + ob;
        cur = nxt;
    }
}

extern "C" void kernel_launch(void* const* d_in, const int* in_sizes, int n_in,
                              void* d_out, int out_size, void* d_ws, size_t ws_size,
                              hipStream_t stream) {
    const float* X    = (const float*)d_in[0];
    const float* p_w  = (const float*)d_in[1];
    const float* p_b  = (const float*)d_in[2];
    const float* c0w1r = (const float*)d_in[3];
    const float* c0w1i = (const float*)d_in[4];
    const float* c0w2r = (const float*)d_in[5];
    const float* c0w2i = (const float*)d_in[6];
    const float* c1w1r = (const float*)d_in[7];
    const float* c1w1i = (const float*)d_in[8];
    const float* c1w2r = (const float*)d_in[9];
    const float* c1w2i = (const float*)d_in[10];
    const float* m0aw = (const float*)d_in[11];
    const float* m0ab = (const float*)d_in[12];
    const float* m0bw = (const float*)d_in[13];
    const float* m0bb = (const float*)d_in[14];
    const float* m1aw = (const float*)d_in[15];
    const float* m1ab = (const float*)d_in[16];
    const float* m1bw = (const float*)d_in[17];
    const float* m1bb = (const float*)d_in[18];
    const float* w0w  = (const float*)d_in[19];
    const float* w0b  = (const float*)d_in[20];
    const float* w1w  = (const float*)d_in[21];
    const float* w1b  = (const float*)d_in[22];
    const float* g0wi = (const float*)d_in[23];
    const float* g0wh = (const float*)d_in[24];
    const float* g0bi = (const float*)d_in[25];
    const float* g0bh = (const float*)d_in[26];
    const float* g1wi = (const float*)d_in[27];
    const float* g1wh = (const float*)d_in[28];
    const float* g1bi = (const float*)d_in[29];
    const float* g1bh = (const float*)d_in[30];
    const float* outw = (const float*)d_in[31];
    const float* outb = (const float*)d_in[32];
    float* out = (float*)d_out;

    float* ws   = (float*)d_ws;
    float* gi0  = ws + GI0_OFF;

    repack_kernel<<<(2 * NPOS * W66 * W66 + 255) / 256, 256, 0, stream>>>(
        c0w1r, c0w1i, c0w2r, c0w2i, c1w1r, c1w1i, c1w2r, c1w2i,
        m0aw, m1aw, m0bw, m1bw, w0w, w1w, ws);

    // A (16632) + Bb (19008) floats = 142560 B
    size_t lds = (size_t)(SPB * SROW + 19008) * sizeof(float);
    hipFuncSetAttribute(reinterpret_cast<const void*>(fno_kernel),
                        hipFuncAttributeMaxDynamicSharedMemorySize, (int)lds);
    int grid = (NSAMP + SPB - 1) / SPB;   // 2341
    fno_kernel<<<grid, NTH, lds, stream>>>(
        X, p_w, p_b, ws,
        m0ab, m1ab, m0bb, m1bb, w0b, w1b,
        g0wi, g0bi, gi0);

    gru_kernel<<<64, 64, 0, stream>>>(gi0, g0wh, g0bh, g1wi, g1wh, g1bi, g1bh, outw, outb, out);
}

// Round 18
// 1731.571 us; speedup vs baseline: 1.1762x; 1.1762x over previous
//
#include <hip/hip_runtime.h>

#define NTH 512          // 8 waves -> 2 waves/SIMD resident
#define SPB 7            // samples per block
#define W66 66
#define PIX36 36
#define NPOS 18
#define FEAT 2376
#define TT 256
#define NSAMP 16384
#define CHU (SPB * W66)  // 462 channel units
#define SROW 2376        // floats per sample row; 2376%32=8
#define XP 7             // xft s-stride (float2), no pad: banks 14*ch+2s spread well

// ws float offsets
#define PACK_FLOATS (2 * NPOS * W66 * W66)    // 313632
#define C1P_OFF  PACK_FLOATS                  // 11616: c1p[L][i][cp][4]
#define C2P_OFF  (C1P_OFF + 11616)            // 23232: c2p[L][i][cp][8]
#define GI0_OFF  (C2P_OFF + 23232)            // 786432: gi0[16384][48]

static constexpr float KC[6] = {1.f, 0.5f, -0.5f, -1.f, -0.5f, 0.5f};
static constexpr float KS[6] = {0.f, 0.8660254037844386468f, 0.8660254037844386468f,
                                0.f, -0.8660254037844386468f, -0.8660254037844386468f};

__device__ __forceinline__ float gelu_f(float v) {
    return 0.5f * v * (1.f + erff(v * 0.70710678118654752440f));
}

__device__ __forceinline__ void load_row36(float* d, const float* p) {
    const float4* r = (const float4*)p;
    #pragma unroll
    for (int q = 0; q < 9; ++q) {
        float4 v = r[q];
        d[4*q] = v.x; d[4*q+1] = v.y; d[4*q+2] = v.z; d[4*q+3] = v.w;
    }
}

extern "C" __global__ void repack_kernel(
    const float* __restrict__ w1r0, const float* __restrict__ w1i0,
    const float* __restrict__ w2r0, const float* __restrict__ w2i0,
    const float* __restrict__ w1r1, const float* __restrict__ w1i1,
    const float* __restrict__ w2r1, const float* __restrict__ w2i1,
    const float* __restrict__ m0aw, const float* __restrict__ m1aw,
    const float* __restrict__ m0bw, const float* __restrict__ m1bw,
    const float* __restrict__ w0w,  const float* __restrict__ w1w,
    float* __restrict__ ws)
{
    int e = blockIdx.x * blockDim.x + threadIdx.x;
    const int TOT = 2 * NPOS * W66 * W66;
    if (e < TOT) {
        int L = e / (NPOS * W66 * W66);
        int r = e % (NPOS * W66 * W66);
        int p = r / (W66 * W66);
        int io = r % (W66 * W66);
        int i = io / W66, o = io % W66;
        int kx = p / 3, ky = p % 3;
        const float *wr, *wi;
        int kxw;
        if (L == 0) { if (kx < 3) { wr = w1r0; wi = w1i0; kxw = kx; } else { wr = w2r0; wi = w2i0; kxw = kx - 3; } }
        else        { if (kx < 3) { wr = w1r1; wi = w1i1; kxw = kx; } else { wr = w2r1; wi = w2i1; kxw = kx - 3; } }
        int src = ((i * W66 + o) * 3 + kxw) * 3 + ky;
        ws[(size_t)e * 2 + 0] = wr[src];
        ws[(size_t)e * 2 + 1] = wi[src];
    }
    if (e < 2 * 66 * 22) {        // c1p
        int L = e / (66 * 22); int r = e % (66 * 22);
        int i = r / 22, cp = r % 22;
        const float* mw = L ? m1aw : m0aw;
        float4 v;
        v.x = mw[(3*cp + 0) * 66 + i];
        v.y = mw[(3*cp + 1) * 66 + i];
        v.z = mw[(3*cp + 2) * 66 + i];
        v.w = 0.f;
        ((float4*)(ws + C1P_OFF))[e] = v;
    }
    if (e < 2 * 66 * 22) {        // c2p
        int L = e / (66 * 22); int r = e % (66 * 22);
        int i = r / 22, cp = r % 22;
        const float* mb = L ? m1bw : m0bw;
        const float* sk = L ? w1w : w0w;
        float4 a, b;
        a.x = mb[(3*cp + 0) * 66 + i]; a.y = mb[(3*cp + 1) * 66 + i];
        a.z = mb[(3*cp + 2) * 66 + i]; a.w = 0.f;
        b.x = sk[(3*cp + 0) * 66 + i]; b.y = sk[(3*cp + 1) * 66 + i];
        b.z = sk[(3*cp + 2) * 66 + i]; b.w = 0.f;
        ((float4*)(ws + C2P_OFF))[(size_t)e * 2 + 0] = a;
        ((float4*)(ws + C2P_OFF))[(size_t)e * 2 + 1] = b;
    }
}

extern "C" __global__ void __launch_bounds__(NTH, 1)
fno_kernel(const float* __restrict__ X, const float* __restrict__ p_w,
           const float* __restrict__ p_b, const float* __restrict__ ws,
           const float* __restrict__ m0ab, const float* __restrict__ m1ab,
           const float* __restrict__ m0bb, const float* __restrict__ m1bb,
           const float* __restrict__ w0b, const float* __restrict__ w1b,
           const float* __restrict__ gwi, const float* __restrict__ gbi,
           float* __restrict__ gi0out)
{
    extern __shared__ float sm[];
    float* A  = sm;                       // rows [s][ch][36], 7*2376 = 16632 floats
    float* Bb = sm + SPB * SROW;          // xft/oft float2 [p][ch][7] (16632 fl) OR rows
    // total 33264 floats = 133056 B

    const int tid = threadIdx.x;
    const int n0 = blockIdx.x * SPB;
    const int s = tid % 7, ch = tid / 7;      // (s,ch) for embed/F/I
    const bool actC = tid < CHU;
    const bool vs = (n0 + s) < NSAMP;
    const int cs = tid % 7, ct = tid / 7;     // conv: (s, hp, cp)
    const int chp = ct % 3, ccp = ct / 3;

    // ---- embed -> A row ----
    if (actC) {
        float h[36];
        float pw0 = p_w[ch], pw1 = p_w[66 + ch], pw2 = p_w[132 + ch], pb = p_b[ch];
        if (vs) {
            const float4* xr = (const float4*)(X + (size_t)(n0 + s) * 36);
            #pragma unroll
            for (int q = 0; q < 9; ++q) {
                float4 v = xr[q];
                float vv[4] = {v.x, v.y, v.z, v.w};
                #pragma unroll
                for (int e = 0; e < 4; ++e) {
                    int pix = 4 * q + e;
                    int px = pix / 6, py = pix % 6;
                    h[pix] = fmaf(vv[e] + 0.01f, pw0,
                              fmaf(px * 0.2f, pw1, fmaf(py * 0.2f, pw2, pb)));
                }
            }
        } else {
            #pragma unroll
            for (int x = 0; x < 36; ++x) h[x] = 0.f;
        }
        float4* r = (float4*)(A + s * SROW + ch * 36);
        #pragma unroll
        for (int q = 0; q < 9; ++q)
            r[q] = make_float4(h[4*q], h[4*q+1], h[4*q+2], h[4*q+3]);
    }
    // no barrier: F reads only this thread's own A row.

    for (int L = 0; L < 2; ++L) {
        const float* mab = L ? m1ab : m0ab;
        const float* mbb = L ? m1bb : m0bb;
        const float* skb = L ? w1b : w0b;
        const float2* packL = ((const float2*)ws) + (size_t)L * NPOS * W66 * W66;
        const float4* c1p = (const float4*)(ws + C1P_OFF) + (size_t)L * 66 * 22;
        const float4* c2p = (const float4*)(ws + C2P_OFF) + (size_t)L * 66 * 22 * 2;

        // ---- F: separable forward DFT + in-reg stats -> xft [p][ch][7] ----
        if (actC) {
            float h[36];
            load_row36(h, A + s * SROW + ch * 36);
            float sum = 0.f, sq = 0.f;
            #pragma unroll
            for (int x = 0; x < 36; ++x) { sum += h[x]; sq = fmaf(h[x], h[x], sq); }
            float hm = sum * (1.f / 36.f);
            float hrs = rsqrtf(sq * (1.f / 36.f) - hm * hm + 1e-5f);
            float tr[6][3], ti[6][3];
            #pragma unroll
            for (int px = 0; px < 6; ++px) {
                float a0 = h[px*6+0], a1 = h[px*6+1], a2 = h[px*6+2];
                float a3 = h[px*6+3], a4 = h[px*6+4], a5 = h[px*6+5];
                float s14 = a1 + a4, d14 = a1 - a4, s25 = a2 + a5, d25 = a2 - a5;
                tr[px][0] = (a0 + a3) + s14 + s25;
                ti[px][0] = 0.f;
                tr[px][1] = (a0 - a3) + 0.5f * (d14 - d25);
                ti[px][1] = -0.8660254037844386468f * (d14 + d25);
                tr[px][2] = (a0 + a3) - 0.5f * (s14 + s25);
                ti[px][2] = -0.8660254037844386468f * (s14 - s25);
            }
            float2* xf = (float2*)Bb;
            #pragma unroll
            for (int kx = 0; kx < 6; ++kx) {
                #pragma unroll
                for (int ky = 0; ky < 3; ++ky) {
                    float xr = 0.f, xi = 0.f;
                    #pragma unroll
                    for (int px = 0; px < 6; ++px) {
                        const int m = (kx * px) % 6;
                        xr += tr[px][ky] * KC[m] + ti[px][ky] * KS[m];
                        xi += ti[px][ky] * KC[m] - tr[px][ky] * KS[m];
                    }
                    if (kx == 0 && ky == 0) xr -= 36.f * hm;
                    xf[((kx * 3 + ky) * 66 + ch) * XP + s] = make_float2(hrs * xr, hrs * xi);
                }
            }
        }
        __syncthreads();  // B1: xft ready

        // ---- M: channel mix, units (p, o-triple) = 396, streaming x, unroll 2 ----
        {
            const bool actM = tid < 396;
            float ar[3][7], ai[3][7];
            int p = 0, o0 = 0;
            if (actM) { p = tid / 22; o0 = (tid - p * 22) * 3; }
            if (actM) {
                #pragma unroll
                for (int j = 0; j < 3; ++j)
                    #pragma unroll
                    for (int q = 0; q < 7; ++q) { ar[j][q] = 0.f; ai[j][q] = 0.f; }
                const float2* xfp = (const float2*)Bb + (size_t)p * 66 * XP;
                const float2* wp = packL + (size_t)p * 66 * 66;
                #pragma unroll 2
                for (int i = 0; i < 66; ++i) {
                    float4 w01 = *(const float4*)(wp + i * 66 + o0);
                    float2 w2  = wp[i * 66 + o0 + 2];
                    #pragma unroll
                    for (int q = 0; q < 7; ++q) {
                        float2 x = xfp[i * XP + q];
                        ar[0][q] = fmaf(x.x, w01.x, ar[0][q]); ar[0][q] = fmaf(x.y, -w01.y, ar[0][q]);
                        ai[0][q] = fmaf(x.x, w01.y, ai[0][q]); ai[0][q] = fmaf(x.y,  w01.x, ai[0][q]);
                        ar[1][q] = fmaf(x.x, w01.z, ar[1][q]); ar[1][q] = fmaf(x.y, -w01.w, ar[1][q]);
                        ai[1][q] = fmaf(x.x, w01.w, ai[1][q]); ai[1][q] = fmaf(x.y,  w01.z, ai[1][q]);
                        ar[2][q] = fmaf(x.x, w2.x, ar[2][q]);  ar[2][q] = fmaf(x.y, -w2.y, ar[2][q]);
                        ai[2][q] = fmaf(x.x, w2.y, ai[2][q]);  ai[2][q] = fmaf(x.y,  w2.x, ai[2][q]);
                    }
                }
            }
            __syncthreads();  // B2: all xft reads done
            if (actM) {
                float2* xf = (float2*)Bb;
                #pragma unroll
                for (int j = 0; j < 3; ++j)
                    #pragma unroll
                    for (int q = 0; q < 7; ++q)
                        xf[((size_t)p * 66 + o0 + j) * XP + q] = make_float2(ar[j][q], ai[j][q]);
            }
        }
        __syncthreads();  // B3: oft ready

        // ---- I: kx-first inverse DFT + stats; writes NORMALIZED rows ----
        {
            float sp[36];
            if (actC) {
                const float2* xf = (const float2*)Bb;
                float ar0[6], ar1[6], ai1[6], ar2[6], ai2[6];
                #pragma unroll
                for (int px = 0; px < 6; ++px) {
                    ar0[px]=0.f; ar1[px]=0.f; ai1[px]=0.f; ar2[px]=0.f; ai2[px]=0.f;
                }
                #pragma unroll
                for (int kx = 0; kx < 6; ++kx) {
                    float2 o0 = xf[((kx * 3 + 0) * 66 + ch) * XP + s];
                    float2 o1 = xf[((kx * 3 + 1) * 66 + ch) * XP + s];
                    float2 o2 = xf[((kx * 3 + 2) * 66 + ch) * XP + s];
                    #pragma unroll
                    for (int px = 0; px < 6; ++px) {
                        const int m = (kx * px) % 6;
                        ar0[px] += o0.x * KC[m] - o0.y * KS[m];
                        ar1[px] += o1.x * KC[m] - o1.y * KS[m];
                        ai1[px] += o1.x * KS[m] + o1.y * KC[m];
                        ar2[px] += o2.x * KC[m] - o2.y * KS[m];
                        ai2[px] += o2.x * KS[m] + o2.y * KC[m];
                    }
                }
                float sum = 0.f, sq = 0.f;
                #pragma unroll
                for (int px = 0; px < 6; ++px) {
                    #pragma unroll
                    for (int py = 0; py < 6; ++py) {
                        const int m2 = (2 * py) % 6;
                        float sv = (1.f/36.f) * ar0[px]
                                 + (1.f/18.f) * (ar1[px] * KC[py] - ai1[px] * KS[py])
                                 + (1.f/18.f) * (ar2[px] * KC[m2] - ai2[px] * KS[m2]);
                        sp[px*6+py] = sv; sum += sv; sq = fmaf(sv, sv, sq);
                    }
                }
                float m = sum * (1.f / 36.f);
                float rs = rsqrtf(sq * (1.f / 36.f) - m * m + 1e-5f);
                #pragma unroll
                for (int x = 0; x < 36; ++x) sp[x] = (sp[x] - m) * rs;
            }
            __syncthreads();  // B4: all oft reads done
            if (actC) {
                float4* r = (float4*)(Bb + s * SROW + ch * 36);
                #pragma unroll
                for (int q = 0; q < 9; ++q)
                    r[q] = make_float4(sp[4*q], sp[4*q+1], sp[4*q+2], sp[4*q+3]);
            }
        }
        __syncthreads();  // B5: normalized rows ready

        // ---- C1: plain conv + gelu; units (s, cp, hp) = 462 ----
        {
            float acc[3][12];
            if (actC) {
                #pragma unroll
                for (int j = 0; j < 3; ++j)
                    #pragma unroll
                    for (int x = 0; x < 12; ++x) acc[j][x] = 0.f;
                #pragma unroll 4
                for (int i = 0; i < 66; ++i) {
                    float4 w = c1p[i * 22 + ccp];
                    const float4* xr = (const float4*)(Bb + cs * SROW + i * 36 + chp * 12);
                    #pragma unroll
                    for (int q = 0; q < 3; ++q) {
                        float4 v = xr[q];
                        float vv[4] = {v.x, v.y, v.z, v.w};
                        #pragma unroll
                        for (int e = 0; e < 4; ++e) {
                            acc[0][4*q+e] = fmaf(w.x, vv[e], acc[0][4*q+e]);
                            acc[1][4*q+e] = fmaf(w.y, vv[e], acc[1][4*q+e]);
                            acc[2][4*q+e] = fmaf(w.z, vv[e], acc[2][4*q+e]);
                        }
                    }
                }
                float b0 = mab[3*ccp], b1 = mab[3*ccp+1], b2 = mab[3*ccp+2];
                #pragma unroll
                for (int x = 0; x < 12; ++x) {
                    acc[0][x] = gelu_f(acc[0][x] + b0);
                    acc[1][x] = gelu_f(acc[1][x] + b1);
                    acc[2][x] = gelu_f(acc[2][x] + b2);
                }
            }
            __syncthreads();  // B6: all reads of normalized rows done
            if (actC) {
                #pragma unroll
                for (int j = 0; j < 3; ++j) {
                    float4* dst = (float4*)(Bb + cs * SROW + (3*ccp+j) * 36 + chp * 12);
                    dst[0] = make_float4(acc[j][0], acc[j][1], acc[j][2],  acc[j][3]);
                    dst[1] = make_float4(acc[j][4], acc[j][5], acc[j][6],  acc[j][7]);
                    dst[2] = make_float4(acc[j][8], acc[j][9], acc[j][10], acc[j][11]);
                }
            }
        }
        __syncthreads();  // B7: t ready

        // ---- C2: conv2 + skip + gelu ----
        {
            float acc[3][12];
            if (actC) {
                #pragma unroll
                for (int j = 0; j < 3; ++j)
                    #pragma unroll
                    for (int x = 0; x < 12; ++x) acc[j][x] = 0.f;
                #pragma unroll 3
                for (int i = 0; i < 66; ++i) {
                    float4 wy = c2p[(i * 22 + ccp) * 2 + 0];
                    float4 wk = c2p[(i * 22 + ccp) * 2 + 1];
                    const float4* tr4 = (const float4*)(Bb + cs * SROW + i * 36 + chp * 12);
                    const float4* ar4 = (const float4*)(A  + cs * SROW + i * 36 + chp * 12);
                    #pragma unroll
                    for (int q = 0; q < 3; ++q) {
                        float4 tv = tr4[q], av = ar4[q];
                        float tvv[4] = {tv.x, tv.y, tv.z, tv.w};
                        float avv[4] = {av.x, av.y, av.z, av.w};
                        #pragma unroll
                        for (int e = 0; e < 4; ++e) {
                            acc[0][4*q+e] = fmaf(wy.x, tvv[e], fmaf(wk.x, avv[e], acc[0][4*q+e]));
                            acc[1][4*q+e] = fmaf(wy.y, tvv[e], fmaf(wk.y, avv[e], acc[1][4*q+e]));
                            acc[2][4*q+e] = fmaf(wy.z, tvv[e], fmaf(wk.z, avv[e], acc[2][4*q+e]));
                        }
                    }
                }
                #pragma unroll
                for (int j = 0; j < 3; ++j) {
                    float bj = mbb[3*ccp+j] + skb[3*ccp+j];
                    #pragma unroll
                    for (int x = 0; x < 12; ++x) acc[j][x] = gelu_f(acc[j][x] + bj);
                }
            }
            __syncthreads();  // B8: all t/A reads done
            if (actC) {
                #pragma unroll
                for (int j = 0; j < 3; ++j) {
                    float4* dst = (float4*)(A + cs * SROW + (3*ccp+j) * 36 + chp * 12);
                    dst[0] = make_float4(acc[j][0], acc[j][1], acc[j][2],  acc[j][3]);
                    dst[1] = make_float4(acc[j][4], acc[j][5], acc[j][6],  acc[j][7]);
                    dst[2] = make_float4(acc[j][8], acc[j][9], acc[j][10], acc[j][11]);
                }
            }
        }
        __syncthreads();  // B9: A rows visible for next F
    }

    // ---- epilogue: gi0 = feats @ Wi0^T + bi0; units (third, es, g) = 1008, 2 passes ----
    #pragma unroll
    for (int rnd = 0; rnd < 2; ++rnd) {
        int u = tid + rnd * NTH;
        if (u < 1008) {
            int third = u / 336, r = u - third * 336;
            int es = r % 7, g = r / 7;
            const float* ab = A + es * SROW + third * 792;
            const float* wb = gwi + (size_t)g * FEAT + third * 792;
            float a0 = 0.f, a1 = 0.f, a2 = 0.f, a3 = 0.f;
            #pragma unroll 2
            for (int w = 0; w < 22; ++w) {
                const float4* ar4 = (const float4*)(ab + w * 36);
                const float4* wr4 = (const float4*)(wb + w * 36);
                #pragma unroll
                for (int q = 0; q < 9; ++q) {
                    float4 av = ar4[q], wv = wr4[q];
                    a0 = fmaf(av.x, wv.x, a0); a1 = fmaf(av.y, wv.y, a1);
                    a2 = fmaf(av.z, wv.z, a2); a3 = fmaf(av.w, wv.w, a3);
                }
            }
            Bb[u] = (a0 + a1) + (a2 + a3);
        }
    }
    __syncthreads();
    if (tid < 336) {
        int es = tid % 7, g = tid / 7;
        if (n0 + es < NSAMP)
            gi0out[(size_t)(n0 + es) * 48 + g] = Bb[tid] + Bb[tid + 336] + Bb[tid + 672] + gbi[g];
    }
}

// fused GRU0 + GRU1 + output linear; one block per batch element, one wave.
extern "C" __global__ void __launch_bounds__(64, 1)
gru_kernel(const float* __restrict__ gi0, const float* __restrict__ wh0,
           const float* __restrict__ bh0, const float* __restrict__ wi1,
           const float* __restrict__ wh1, const float* __restrict__ bi1,
           const float* __restrict__ bh1, const float* __restrict__ outw,
           const float* __restrict__ outb, float* __restrict__ y)
{
    int b = blockIdx.x;
    int g = threadIdx.x;
    int gw = (g < 48) ? g : 0;
    float rwh0[16], rwi1[16], rwh1[16];
    #pragma unroll
    for (int j = 0; j < 16; ++j) {
        rwh0[j] = wh0[gw * 16 + j];
        rwi1[j] = wi1[gw * 16 + j];
        rwh1[j] = wh1[gw * 16 + j];
    }
    float vbh0 = bh0[gw], vbi1 = bi1[gw], vbh1 = bh1[gw];
    float vow = (g < 16) ? outw[g] : 0.f;
    float ob = outb[0];
    float h0 = 0.f, h1 = 0.f;
    int base = b * TT;
    int j = g & 15;
    float cur = (g < 48) ? gi0[(size_t)base * 48 + g] : 0.f;
    for (int t = 0; t < TT; ++t) {
        int tn = (t + 1 < TT) ? t + 1 : t;
        float nxt = (g < 48) ? gi0[((size_t)base + tn) * 48 + g] : 0.f;
        float gh0 = vbh0;
        #pragma unroll
        for (int k = 0; k < 16; ++k) gh0 = fmaf(rwh0[k], __shfl(h0, k), gh0);
        float gir = __shfl(cur, j), giz = __shfl(cur, 16 + j), gin = __shfl(cur, 32 + j);
        float ghr = __shfl(gh0, j), ghz = __shfl(gh0, 16 + j), ghn = __shfl(gh0, 32 + j);
        float r = 1.f / (1.f + expf(-(gir + ghr)));
        float z = 1.f / (1.f + expf(-(giz + ghz)));
        float n = tanhf(gin + r * ghn);
        h0 = (1.f - z) * n + z * h0;
        float gi1 = vbi1, gh1 = vbh1;
        #pragma unroll
        for (int k = 0; k < 16; ++k) {
            gi1 = fmaf(rwi1[k], __shfl(h0, k), gi1);
            gh1 = fmaf(rwh1[k], __shfl(h1, k), gh1);
        }
        float air = __shfl(gi1, j) + __shfl(gh1, j);
        float aiz = __shfl(gi1, 16 + j) + __shfl(gh1, 16 + j);
        float r1 = 1.f / (1.f + expf(-air));
        float z1 = 1.f / (1.f + expf(-aiz));
        float n1 = tanhf(__shfl(gi1, 32 + j) + r1 * __shfl(gh1, 32 + j));
        h1 = (1.f - z1) * n1 + z1 * h1;
        float v = h1 * vow;
        #pragma unroll
        for (int off = 32; off; off >>= 1) v += __shfl_xor(v, off);
        if (g == 0) y[base + t] = v + ob;
        cur = nxt;
    }
}

extern "C" void kernel_launch(void* const* d_in, const int* in_sizes, int n_in,
                              void* d_out, int out_size, void* d_ws, size_t ws_size,
                              hipStream_t stream) {
    const float* X    = (const float*)d_in[0];
    const float* p_w  = (const float*)d_in[1];
    const float* p_b  = (const float*)d_in[2];
    const float* c0w1r = (const float*)d_in[3];
    const float* c0w1i = (const float*)d_in[4];
    const float* c0w2r = (const float*)d_in[5];
    const float* c0w2i = (const float*)d_in[6];
    const float* c1w1r = (const float*)d_in[7];
    const float* c1w1i = (const float*)d_in[8];
    const float* c1w2r = (const float*)d_in[9];
    const float* c1w2i = (const float*)d_in[10];
    const float* m0aw = (const float*)d_in[11];
    const float* m0ab = (const float*)d_in[12];
    const float* m0bw = (const float*)d_in[13];
    const float* m0bb = (const float*)d_in[14];
    const float* m1aw = (const float*)d_in[15];
    const float* m1ab = (const float*)d_in[16];
    const float* m1bw = (const float*)d_in[17];
    const float* m1bb = (const float*)d_in[18];
    const float* w0w  = (const float*)d_in[19];
    const float* w0b  = (const float*)d_in[20];
    const float* w1w  = (const float*)d_in[21];
    const float* w1b  = (const float*)d_in[22];
    const float* g0wi = (const float*)d_in[23];
    const float* g0wh = (const float*)d_in[24];
    const float* g0bi = (const float*)d_in[25];
    const float* g0bh = (const float*)d_in[26];
    const float* g1wi = (const float*)d_in[27];
    const float* g1wh = (const float*)d_in[28];
    const float* g1bi = (const float*)d_in[29];
    const float* g1bh = (const float*)d_in[30];
    const float* outw = (const float*)d_in[31];
    const float* outb = (const float*)d_in[32];
    float* out = (float*)d_out;

    float* ws   = (float*)d_ws;
    float* gi0  = ws + GI0_OFF;

    repack_kernel<<<(2 * NPOS * W66 * W66 + 255) / 256, 256, 0, stream>>>(
        c0w1r, c0w1i, c0w2r, c0w2i, c1w1r, c1w1i, c1w2r, c1w2i,
        m0aw, m1aw, m0bw, m1bw, w0w, w1w, ws);

    // A (16632) + Bb (16632) floats = 133056 B
    size_t lds = (size_t)(2 * SPB * SROW) * sizeof(float);
    hipFuncSetAttribute(reinterpret_cast<const void*>(fno_kernel),
                        hipFuncAttributeMaxDynamicSharedMemorySize, (int)lds);
    int grid = (NSAMP + SPB - 1) / SPB;   // 2341
    fno_kernel<<<grid, NTH, lds, stream>>>(
        X, p_w, p_b, ws,
        m0ab, m1ab, m0bb, m1bb, w0b, w1b,
        g0wi, g0bi, gi0);

    gru_kernel<<<64, 64, 0, stream>>>(gi0, g0wh, g0bh, g1wi, g1wh, g1bi, g1bh, outw, outb, out);
}

// Round 19
// 1641.279 us; speedup vs baseline: 1.2409x; 1.0550x over previous
//
#include <hip/hip_runtime.h>

#define NTH 512          // 8 waves -> 2 waves/SIMD resident
#define SPB 7            // samples per block
#define W66 66
#define PIX36 36
#define NPOS 18
#define FEAT 2376
#define TT 256
#define NSAMP 16384
#define CHU (SPB * W66)  // 462 channel units
#define SROW 2376        // floats per sample row; 2376%32=8
#define XP 7             // xft s-stride (float2)

// ws float offsets
#define PACK_FLOATS (2 * NPOS * W66 * W66)    // 313632
#define C1P_OFF  PACK_FLOATS                  // 11616: c1p[L][i][cp][4]
#define C2P_OFF  (C1P_OFF + 11616)            // 23232: c2p[L][i][cp][8]
#define GI0_OFF  (C2P_OFF + 23232)            // 786432: gi0[16384][48]

static constexpr float KC[6] = {1.f, 0.5f, -0.5f, -1.f, -0.5f, 0.5f};
static constexpr float KS[6] = {0.f, 0.8660254037844386468f, 0.8660254037844386468f,
                                0.f, -0.8660254037844386468f, -0.8660254037844386468f};

__device__ __forceinline__ float gelu_f(float v) {
    return 0.5f * v * (1.f + erff(v * 0.70710678118654752440f));
}

__device__ __forceinline__ void load_row36(float* d, const float* p) {
    const float4* r = (const float4*)p;
    #pragma unroll
    for (int q = 0; q < 9; ++q) {
        float4 v = r[q];
        d[4*q] = v.x; d[4*q+1] = v.y; d[4*q+2] = v.z; d[4*q+3] = v.w;
    }
}

extern "C" __global__ void repack_kernel(
    const float* __restrict__ w1r0, const float* __restrict__ w1i0,
    const float* __restrict__ w2r0, const float* __restrict__ w2i0,
    const float* __restrict__ w1r1, const float* __restrict__ w1i1,
    const float* __restrict__ w2r1, const float* __restrict__ w2i1,
    const float* __restrict__ m0aw, const float* __restrict__ m1aw,
    const float* __restrict__ m0bw, const float* __restrict__ m1bw,
    const float* __restrict__ w0w,  const float* __restrict__ w1w,
    float* __restrict__ ws)
{
    int e = blockIdx.x * blockDim.x + threadIdx.x;
    const int TOT = 2 * NPOS * W66 * W66;
    if (e < TOT) {
        int L = e / (NPOS * W66 * W66);
        int r = e % (NPOS * W66 * W66);
        int p = r / (W66 * W66);
        int io = r % (W66 * W66);
        int i = io / W66, o = io % W66;
        int kx = p / 3, ky = p % 3;
        const float *wr, *wi;
        int kxw;
        if (L == 0) { if (kx < 3) { wr = w1r0; wi = w1i0; kxw = kx; } else { wr = w2r0; wi = w2i0; kxw = kx - 3; } }
        else        { if (kx < 3) { wr = w1r1; wi = w1i1; kxw = kx; } else { wr = w2r1; wi = w2i1; kxw = kx - 3; } }
        int src = ((i * W66 + o) * 3 + kxw) * 3 + ky;
        ws[(size_t)e * 2 + 0] = wr[src];
        ws[(size_t)e * 2 + 1] = wi[src];
    }
    if (e < 2 * 66 * 22) {        // c1p
        int L = e / (66 * 22); int r = e % (66 * 22);
        int i = r / 22, cp = r % 22;
        const float* mw = L ? m1aw : m0aw;
        float4 v;
        v.x = mw[(3*cp + 0) * 66 + i];
        v.y = mw[(3*cp + 1) * 66 + i];
        v.z = mw[(3*cp + 2) * 66 + i];
        v.w = 0.f;
        ((float4*)(ws + C1P_OFF))[e] = v;
    }
    if (e < 2 * 66 * 22) {        // c2p
        int L = e / (66 * 22); int r = e % (66 * 22);
        int i = r / 22, cp = r % 22;
        const float* mb = L ? m1bw : m0bw;
        const float* sk = L ? w1w : w0w;
        float4 a, b;
        a.x = mb[(3*cp + 0) * 66 + i]; a.y = mb[(3*cp + 1) * 66 + i];
        a.z = mb[(3*cp + 2) * 66 + i]; a.w = 0.f;
        b.x = sk[(3*cp + 0) * 66 + i]; b.y = sk[(3*cp + 1) * 66 + i];
        b.z = sk[(3*cp + 2) * 66 + i]; b.w = 0.f;
        ((float4*)(ws + C2P_OFF))[(size_t)e * 2 + 0] = a;
        ((float4*)(ws + C2P_OFF))[(size_t)e * 2 + 1] = b;
    }
}

extern "C" __global__ void __launch_bounds__(NTH, 1)
fno_kernel(const float* __restrict__ X, const float* __restrict__ p_w,
           const float* __restrict__ p_b, const float* __restrict__ ws,
           const float* __restrict__ m0ab, const float* __restrict__ m1ab,
           const float* __restrict__ m0bb, const float* __restrict__ m1bb,
           const float* __restrict__ w0b, const float* __restrict__ w1b,
           const float* __restrict__ gwi, const float* __restrict__ gbi,
           float* __restrict__ gi0out)
{
    extern __shared__ float sm[];
    float* A  = sm;                       // rows [s][ch][36], 7*2376 = 16632 floats
    float* Bb = sm + SPB * SROW;          // xft/oft float2 [p][ch][7] OR rows

    const int tid = threadIdx.x;
    const int n0 = blockIdx.x * SPB;
    const int s = tid % 7, ch = tid / 7;      // (s,ch) for embed/F/I
    const bool actC = tid < CHU;
    const bool vs = (n0 + s) < NSAMP;
    const int cs = tid % 7, ct = tid / 7;     // conv: (s, hp, cp)
    const int chp = ct % 3, ccp = ct / 3;

    // ---- embed -> A row ----
    if (actC) {
        float h[36];
        float pw0 = p_w[ch], pw1 = p_w[66 + ch], pw2 = p_w[132 + ch], pb = p_b[ch];
        if (vs) {
            const float4* xr = (const float4*)(X + (size_t)(n0 + s) * 36);
            #pragma unroll
            for (int q = 0; q < 9; ++q) {
                float4 v = xr[q];
                float vv[4] = {v.x, v.y, v.z, v.w};
                #pragma unroll
                for (int e = 0; e < 4; ++e) {
                    int pix = 4 * q + e;
                    int px = pix / 6, py = pix % 6;
                    h[pix] = fmaf(vv[e] + 0.01f, pw0,
                              fmaf(px * 0.2f, pw1, fmaf(py * 0.2f, pw2, pb)));
                }
            }
        } else {
            #pragma unroll
            for (int x = 0; x < 36; ++x) h[x] = 0.f;
        }
        float4* r = (float4*)(A + s * SROW + ch * 36);
        #pragma unroll
        for (int q = 0; q < 9; ++q)
            r[q] = make_float4(h[4*q], h[4*q+1], h[4*q+2], h[4*q+3]);
    }
    // no barrier: F reads only this thread's own A row.

    for (int L = 0; L < 2; ++L) {
        const float* mab = L ? m1ab : m0ab;
        const float* mbb = L ? m1bb : m0bb;
        const float* skb = L ? w1b : w0b;
        const float2* packL = ((const float2*)ws) + (size_t)L * NPOS * W66 * W66;
        const float4* c1p = (const float4*)(ws + C1P_OFF) + (size_t)L * 66 * 22;
        const float4* c2p = (const float4*)(ws + C2P_OFF) + (size_t)L * 66 * 22 * 2;

        // ---- F: separable forward DFT + in-reg stats -> xft [p][ch][7] ----
        if (actC) {
            float h[36];
            load_row36(h, A + s * SROW + ch * 36);
            float sum = 0.f, sq = 0.f;
            #pragma unroll
            for (int x = 0; x < 36; ++x) { sum += h[x]; sq = fmaf(h[x], h[x], sq); }
            float hm = sum * (1.f / 36.f);
            float hrs = rsqrtf(sq * (1.f / 36.f) - hm * hm + 1e-5f);
            float tr[6][3], ti[6][3];
            #pragma unroll
            for (int px = 0; px < 6; ++px) {
                float a0 = h[px*6+0], a1 = h[px*6+1], a2 = h[px*6+2];
                float a3 = h[px*6+3], a4 = h[px*6+4], a5 = h[px*6+5];
                float s14 = a1 + a4, d14 = a1 - a4, s25 = a2 + a5, d25 = a2 - a5;
                tr[px][0] = (a0 + a3) + s14 + s25;
                ti[px][0] = 0.f;
                tr[px][1] = (a0 - a3) + 0.5f * (d14 - d25);
                ti[px][1] = -0.8660254037844386468f * (d14 + d25);
                tr[px][2] = (a0 + a3) - 0.5f * (s14 + s25);
                ti[px][2] = -0.8660254037844386468f * (s14 - s25);
            }
            float2* xf = (float2*)Bb;
            #pragma unroll
            for (int kx = 0; kx < 6; ++kx) {
                #pragma unroll
                for (int ky = 0; ky < 3; ++ky) {
                    float xr = 0.f, xi = 0.f;
                    #pragma unroll
                    for (int px = 0; px < 6; ++px) {
                        const int m = (kx * px) % 6;
                        xr += tr[px][ky] * KC[m] + ti[px][ky] * KS[m];
                        xi += ti[px][ky] * KC[m] - tr[px][ky] * KS[m];
                    }
                    if (kx == 0 && ky == 0) xr -= 36.f * hm;
                    xf[((kx * 3 + ky) * 66 + ch) * XP + s] = make_float2(hrs * xr, hrs * xi);
                }
            }
        }
        __syncthreads();  // B1: xft ready

        // ---- M: channel mix, units (p, o-triple) = 396, streaming x, unroll 2 ----
        {
            const bool actM = tid < 396;
            float ar[3][7], ai[3][7];
            int p = 0, o0 = 0;
            if (actM) { p = tid / 22; o0 = (tid - p * 22) * 3; }
            if (actM) {
                #pragma unroll
                for (int j = 0; j < 3; ++j)
                    #pragma unroll
                    for (int q = 0; q < 7; ++q) { ar[j][q] = 0.f; ai[j][q] = 0.f; }
                const float2* xfp = (const float2*)Bb + (size_t)p * 66 * XP;
                const float2* wp = packL + (size_t)p * 66 * 66;
                #pragma unroll 2
                for (int i = 0; i < 66; ++i) {
                    float4 w01 = *(const float4*)(wp + i * 66 + o0);
                    float2 w2  = wp[i * 66 + o0 + 2];
                    #pragma unroll
                    for (int q = 0; q < 7; ++q) {
                        float2 x = xfp[i * XP + q];
                        ar[0][q] = fmaf(x.x, w01.x, ar[0][q]); ar[0][q] = fmaf(x.y, -w01.y, ar[0][q]);
                        ai[0][q] = fmaf(x.x, w01.y, ai[0][q]); ai[0][q] = fmaf(x.y,  w01.x, ai[0][q]);
                        ar[1][q] = fmaf(x.x, w01.z, ar[1][q]); ar[1][q] = fmaf(x.y, -w01.w, ar[1][q]);
                        ai[1][q] = fmaf(x.x, w01.w, ai[1][q]); ai[1][q] = fmaf(x.y,  w01.z, ai[1][q]);
                        ar[2][q] = fmaf(x.x, w2.x, ar[2][q]);  ar[2][q] = fmaf(x.y, -w2.y, ar[2][q]);
                        ai[2][q] = fmaf(x.x, w2.y, ai[2][q]);  ai[2][q] = fmaf(x.y,  w2.x, ai[2][q]);
                    }
                }
            }
            __syncthreads();  // B2: all xft reads done
            if (actM) {
                float2* xf = (float2*)Bb;
                #pragma unroll
                for (int j = 0; j < 3; ++j)
                    #pragma unroll
                    for (int q = 0; q < 7; ++q)
                        xf[((size_t)p * 66 + o0 + j) * XP + q] = make_float2(ar[j][q], ai[j][q]);
            }
        }
        __syncthreads();  // B3: oft ready

        // ---- I: kx-first inverse DFT + stats; writes NORMALIZED rows ----
        {
            float sp[36];
            if (actC) {
                const float2* xf = (const float2*)Bb;
                float ar0[6], ar1[6], ai1[6], ar2[6], ai2[6];
                #pragma unroll
                for (int px = 0; px < 6; ++px) {
                    ar0[px]=0.f; ar1[px]=0.f; ai1[px]=0.f; ar2[px]=0.f; ai2[px]=0.f;
                }
                #pragma unroll
                for (int kx = 0; kx < 6; ++kx) {
                    float2 o0 = xf[((kx * 3 + 0) * 66 + ch) * XP + s];
                    float2 o1 = xf[((kx * 3 + 1) * 66 + ch) * XP + s];
                    float2 o2 = xf[((kx * 3 + 2) * 66 + ch) * XP + s];
                    #pragma unroll
                    for (int px = 0; px < 6; ++px) {
                        const int m = (kx * px) % 6;
                        ar0[px] += o0.x * KC[m] - o0.y * KS[m];
                        ar1[px] += o1.x * KC[m] - o1.y * KS[m];
                        ai1[px] += o1.x * KS[m] + o1.y * KC[m];
                        ar2[px] += o2.x * KC[m] - o2.y * KS[m];
                        ai2[px] += o2.x * KS[m] + o2.y * KC[m];
                    }
                }
                float sum = 0.f, sq = 0.f;
                #pragma unroll
                for (int px = 0; px < 6; ++px) {
                    #pragma unroll
                    for (int py = 0; py < 6; ++py) {
                        const int m2 = (2 * py) % 6;
                        float sv = (1.f/36.f) * ar0[px]
                                 + (1.f/18.f) * (ar1[px] * KC[py] - ai1[px] * KS[py])
                                 + (1.f/18.f) * (ar2[px] * KC[m2] - ai2[px] * KS[m2]);
                        sp[px*6+py] = sv; sum += sv; sq = fmaf(sv, sv, sq);
                    }
                }
                float m = sum * (1.f / 36.f);
                float rs = rsqrtf(sq * (1.f / 36.f) - m * m + 1e-5f);
                #pragma unroll
                for (int x = 0; x < 36; ++x) sp[x] = (sp[x] - m) * rs;
            }
            __syncthreads();  // B4: all oft reads done
            if (actC) {
                float4* r = (float4*)(Bb + s * SROW + ch * 36);
                #pragma unroll
                for (int q = 0; q < 9; ++q)
                    r[q] = make_float4(sp[4*q], sp[4*q+1], sp[4*q+2], sp[4*q+3]);
            }
        }
        __syncthreads();  // B5: normalized rows ready

        // ---- C1: plain conv + gelu; units (s, cp, hp) = 462, unroll 3 ----
        {
            float acc[3][12];
            if (actC) {
                #pragma unroll
                for (int j = 0; j < 3; ++j)
                    #pragma unroll
                    for (int x = 0; x < 12; ++x) acc[j][x] = 0.f;
                #pragma unroll 3
                for (int i = 0; i < 66; ++i) {
                    float4 w = c1p[i * 22 + ccp];
                    const float4* xr = (const float4*)(Bb + cs * SROW + i * 36 + chp * 12);
                    #pragma unroll
                    for (int q = 0; q < 3; ++q) {
                        float4 v = xr[q];
                        float vv[4] = {v.x, v.y, v.z, v.w};
                        #pragma unroll
                        for (int e = 0; e < 4; ++e) {
                            acc[0][4*q+e] = fmaf(w.x, vv[e], acc[0][4*q+e]);
                            acc[1][4*q+e] = fmaf(w.y, vv[e], acc[1][4*q+e]);
                            acc[2][4*q+e] = fmaf(w.z, vv[e], acc[2][4*q+e]);
                        }
                    }
                }
                float b0 = mab[3*ccp], b1 = mab[3*ccp+1], b2 = mab[3*ccp+2];
                #pragma unroll
                for (int x = 0; x < 12; ++x) {
                    acc[0][x] = gelu_f(acc[0][x] + b0);
                    acc[1][x] = gelu_f(acc[1][x] + b1);
                    acc[2][x] = gelu_f(acc[2][x] + b2);
                }
            }
            __syncthreads();  // B6: all reads of normalized rows done
            if (actC) {
                #pragma unroll
                for (int j = 0; j < 3; ++j) {
                    float4* dst = (float4*)(Bb + cs * SROW + (3*ccp+j) * 36 + chp * 12);
                    dst[0] = make_float4(acc[j][0], acc[j][1], acc[j][2],  acc[j][3]);
                    dst[1] = make_float4(acc[j][4], acc[j][5], acc[j][6],  acc[j][7]);
                    dst[2] = make_float4(acc[j][8], acc[j][9], acc[j][10], acc[j][11]);
                }
            }
        }
        __syncthreads();  // B7: t ready

        // ---- C2: conv2 + skip + gelu, unroll 2 ----
        {
            float acc[3][12];
            if (actC) {
                #pragma unroll
                for (int j = 0; j < 3; ++j)
                    #pragma unroll
                    for (int x = 0; x < 12; ++x) acc[j][x] = 0.f;
                #pragma unroll 2
                for (int i = 0; i < 66; ++i) {
                    float4 wy = c2p[(i * 22 + ccp) * 2 + 0];
                    float4 wk = c2p[(i * 22 + ccp) * 2 + 1];
                    const float4* tr4 = (const float4*)(Bb + cs * SROW + i * 36 + chp * 12);
                    const float4* ar4 = (const float4*)(A  + cs * SROW + i * 36 + chp * 12);
                    #pragma unroll
                    for (int q = 0; q < 3; ++q) {
                        float4 tv = tr4[q], av = ar4[q];
                        float tvv[4] = {tv.x, tv.y, tv.z, tv.w};
                        float avv[4] = {av.x, av.y, av.z, av.w};
                        #pragma unroll
                        for (int e = 0; e < 4; ++e) {
                            acc[0][4*q+e] = fmaf(wy.x, tvv[e], fmaf(wk.x, avv[e], acc[0][4*q+e]));
                            acc[1][4*q+e] = fmaf(wy.y, tvv[e], fmaf(wk.y, avv[e], acc[1][4*q+e]));
                            acc[2][4*q+e] = fmaf(wy.z, tvv[e], fmaf(wk.z, avv[e], acc[2][4*q+e]));
                        }
                    }
                }
                #pragma unroll
                for (int j = 0; j < 3; ++j) {
                    float bj = mbb[3*ccp+j] + skb[3*ccp+j];
                    #pragma unroll
                    for (int x = 0; x < 12; ++x) acc[j][x] = gelu_f(acc[j][x] + bj);
                }
            }
            __syncthreads();  // B8: all t/A reads done
            if (actC) {
                #pragma unroll
                for (int j = 0; j < 3; ++j) {
                    float4* dst = (float4*)(A + cs * SROW + (3*ccp+j) * 36 + chp * 12);
                    dst[0] = make_float4(acc[j][0], acc[j][1], acc[j][2],  acc[j][3]);
                    dst[1] = make_float4(acc[j][4], acc[j][5], acc[j][6],  acc[j][7]);
                    dst[2] = make_float4(acc[j][8], acc[j][9], acc[j][10], acc[j][11]);
                }
            }
        }
        __syncthreads();  // B9: A rows visible for next F
    }

    // ---- epilogue: gi0 = feats @ Wi0^T + bi0; units (third, es, g) = 1008, 2 passes ----
    #pragma unroll
    for (int rnd = 0; rnd < 2; ++rnd) {
        int u = tid + rnd * NTH;
        if (u < 1008) {
            int third = u / 336, r = u - third * 336;
            int es = r % 7, g = r / 7;
            const float* ab = A + es * SROW + third * 792;
            const float* wb = gwi + (size_t)g * FEAT + third * 792;
            float a0 = 0.f, a1 = 0.f, a2 = 0.f, a3 = 0.f;
            #pragma unroll 2
            for (int w = 0; w < 22; ++w) {
                const float4* ar4 = (const float4*)(ab + w * 36);
                const float4* wr4 = (const float4*)(wb + w * 36);
                #pragma unroll
                for (int q = 0; q < 9; ++q) {
                    float4 av = ar4[q], wv = wr4[q];
                    a0 = fmaf(av.x, wv.x, a0); a1 = fmaf(av.y, wv.y, a1);
                    a2 = fmaf(av.z, wv.z, a2); a3 = fmaf(av.w, wv.w, a3);
                }
            }
            Bb[u] = (a0 + a1) + (a2 + a3);
        }
    }
    __syncthreads();
    if (tid < 336) {
        int es = tid % 7, g = tid / 7;
        if (n0 + es < NSAMP)
            gi0out[(size_t)(n0 + es) * 48 + g] = Bb[tid] + Bb[tid + 336] + Bb[tid + 672] + gbi[g];
    }
}

// fused GRU0 + GRU1 + output linear; one block per batch element, one wave.
extern "C" __global__ void __launch_bounds__(64, 1)
gru_kernel(const float* __restrict__ gi0, const float* __restrict__ wh0,
           const float* __restrict__ bh0, const float* __restrict__ wi1,
           const float* __restrict__ wh1, const float* __restrict__ bi1,
           const float* __restrict__ bh1, const float* __restrict__ outw,
           const float* __restrict__ outb, float* __restrict__ y)
{
    int b = blockIdx.x;
    int g = threadIdx.x;
    int gw = (g < 48) ? g : 0;
    float rwh0[16], rwi1[16], rwh1[16];
    #pragma unroll
    for (int j = 0; j < 16; ++j) {
        rwh0[j] = wh0[gw * 16 + j];
        rwi1[j] = wi1[gw * 16 + j];
        rwh1[j] = wh1[gw * 16 + j];
    }
    float vbh0 = bh0[gw], vbi1 = bi1[gw], vbh1 = bh1[gw];
    float vow = (g < 16) ? outw[g] : 0.f;
    float ob = outb[0];
    float h0 = 0.f, h1 = 0.f;
    int base = b * TT;
    int j = g & 15;
    float cur = (g < 48) ? gi0[(size_t)base * 48 + g] : 0.f;
    for (int t = 0; t < TT; ++t) {
        int tn = (t + 1 < TT) ? t + 1 : t;
        float nxt = (g < 48) ? gi0[((size_t)base + tn) * 48 + g] : 0.f;
        float gh0 = vbh0;
        #pragma unroll
        for (int k = 0; k < 16; ++k) gh0 = fmaf(rwh0[k], __shfl(h0, k), gh0);
        float gir = __shfl(cur, j), giz = __shfl(cur, 16 + j), gin = __shfl(cur, 32 + j);
        float ghr = __shfl(gh0, j), ghz = __shfl(gh0, 16 + j), ghn = __shfl(gh0, 32 + j);
        float r = 1.f / (1.f + expf(-(gir + ghr)));
        float z = 1.f / (1.f + expf(-(giz + ghz)));
        float n = tanhf(gin + r * ghn);
        h0 = (1.f - z) * n + z * h0;
        float gi1 = vbi1, gh1 = vbh1;
        #pragma unroll
        for (int k = 0; k < 16; ++k) {
            gi1 = fmaf(rwi1[k], __shfl(h0, k), gi1);
            gh1 = fmaf(rwh1[k], __shfl(h1, k), gh1);
        }
        float air = __shfl(gi1, j) + __shfl(gh1, j);
        float aiz = __shfl(gi1, 16 + j) + __shfl(gh1, 16 + j);
        float r1 = 1.f / (1.f + expf(-air));
        float z1 = 1.f / (1.f + expf(-aiz));
        float n1 = tanhf(__shfl(gi1, 32 + j) + r1 * __shfl(gh1, 32 + j));
        h1 = (1.f - z1) * n1 + z1 * h1;
        float v = h1 * vow;
        #pragma unroll
        for (int off = 32; off; off >>= 1) v += __shfl_xor(v, off);
        if (g == 0) y[base + t] = v + ob;
        cur = nxt;
    }
}

extern "C" void kernel_launch(void* const* d_in, const int* in_sizes, int n_in,
                              void* d_out, int out_size, void* d_ws, size_t ws_size,
                              hipStream_t stream) {
    const float* X    = (const float*)d_in[0];
    const float* p_w  = (const float*)d_in[1];
    const float* p_b  = (const float*)d_in[2];
    const float* c0w1r = (const float*)d_in[3];
    const float* c0w1i = (const float*)d_in[4];
    const float* c0w2r = (const float*)d_in[5];
    const float* c0w2i = (const float*)d_in[6];
    const float* c1w1r = (const float*)d_in[7];
    const float* c1w1i = (const float*)d_in[8];
    const float* c1w2r = (const float*)d_in[9];
    const float* c1w2i = (const float*)d_in[10];
    const float* m0aw = (const float*)d_in[11];
    const float* m0ab = (const float*)d_in[12];
    const float* m0bw = (const float*)d_in[13];
    const float* m0bb = (const float*)d_in[14];
    const float* m1aw = (const float*)d_in[15];
    const float* m1ab = (const float*)d_in[16];
    const float* m1bw = (const float*)d_in[17];
    const float* m1bb = (const float*)d_in[18];
    const float* w0w  = (const float*)d_in[19];
    const float* w0b  = (const float*)d_in[20];
    const float* w1w  = (const float*)d_in[21];
    const float* w1b  = (const float*)d_in[22];
    const float* g0wi = (const float*)d_in[23];
    const float* g0wh = (const float*)d_in[24];
    const float* g0bi = (const float*)d_in[25];
    const float* g0bh = (const float*)d_in[26];
    const float* g1wi = (const float*)d_in[27];
    const float* g1wh = (const float*)d_in[28];
    const float* g1bi = (const float*)d_in[29];
    const float* g1bh = (const float*)d_in[30];
    const float* outw = (const float*)d_in[31];
    const float* outb = (const float*)d_in[32];
    float* out = (float*)d_out;

    float* ws   = (float*)d_ws;
    float* gi0  = ws + GI0_OFF;

    repack_kernel<<<(2 * NPOS * W66 * W66 + 255) / 256, 256, 0, stream>>>(
        c0w1r, c0w1i, c0w2r, c0w2i, c1w1r, c1w1i, c1w2r, c1w2i,
        m0aw, m1aw, m0bw, m1bw, w0w, w1w, ws);

    // A (16632) + Bb (16632) floats = 133056 B
    size_t lds = (size_t)(2 * SPB * SROW) * sizeof(float);
    hipFuncSetAttribute(reinterpret_cast<const void*>(fno_kernel),
                        hipFuncAttributeMaxDynamicSharedMemorySize, (int)lds);
    int grid = (NSAMP + SPB - 1) / SPB;   // 2341
    fno_kernel<<<grid, NTH, lds, stream>>>(
        X, p_w, p_b, ws,
        m0ab, m1ab, m0bb, m1bb, w0b, w1b,
        g0wi, g0bi, gi0);

    gru_kernel<<<64, 64, 0, stream>>>(gi0, g0wh, g0bh, g1wi, g1wh, g1bi, g1bh, outw, outb, out);
}